// Round 4
// baseline (485.824 us; speedup 1.0000x reference)
//
#include <hip/hip_runtime.h>

#define Dm 512
#define Fm 2048
#define Mm 8192    // B*S tokens
#define KTOT 18432 // 9*Fm

typedef __attribute__((ext_vector_type(8))) short short8;
typedef __attribute__((ext_vector_type(4))) float f32x4;

// ---------- helpers ----------

__device__ __forceinline__ unsigned short f2bf(float f) {
  unsigned u = __builtin_bit_cast(unsigned, f);
  u = (u + 0x7FFFu + ((u >> 16) & 1u)) >> 16;
  return (unsigned short)u;
}

__device__ __forceinline__ float fast_exp2(float x) {
  float r; asm("v_exp_f32 %0, %1" : "=v"(r) : "v"(x)); return r;
}
__device__ __forceinline__ float fast_rcp(float x) {
  float r; asm("v_rcp_f32 %0, %1" : "=v"(r) : "v"(x)); return r;
}

__device__ __forceinline__ void gload_lds16(const void* g, void* lp) {
  __builtin_amdgcn_global_load_lds(
      (const __attribute__((address_space(1))) void*)(unsigned long long)(g),
      (__attribute__((address_space(3))) void*)(unsigned)(unsigned long long)(lp),
      16, 0, 0);
}

__device__ __forceinline__ f32x4 mfma16(short8 a, short8 b, f32x4 c) {
  asm("v_mfma_f32_16x16x32_bf16 %0, %1, %2, %0" : "+v"(c) : "v"(a), "v"(b));
  return c;
}

// Fused wait+barrier as ONE memory-clobber asm: a full compiler memory fence.
// vmcnt(6) is placement-independent-safe here: every stage has >=6 VMEM ops
// issued after it before its wait, so "all but newest 6 complete" always
// covers the stage being consumed.
#define WAIT_BARRIER(n) asm volatile("s_waitcnt vmcnt(" #n ")\n\ts_barrier" ::: "memory")

// B row permutation within each 32-row block: LDS row (32a + 16n + c) holds
// global col (32a + 2c + n)  => frag ni, lane c -> global col 2c + ni
// (thread's 2 output columns contiguous).
#define BPERM2(r) (((r) & 32) | (((r) & 15) << 1) | (((r) >> 4) & 1))

// ---------- prep kernels ----------

__global__ void cvtx_k(const float* __restrict__ src, unsigned short* __restrict__ dst, int n) {
  int i = (blockIdx.x * 256 + threadIdx.x) * 4;
  if (i >= n) return;
  const float4 v = *(const float4*)(src + i);
  unsigned a = (unsigned)f2bf(v.x) | ((unsigned)f2bf(v.y) << 16);
  unsigned b = (unsigned)f2bf(v.z) | ((unsigned)f2bf(v.w) << 16);
  uint2 o; o.x = a; o.y = b;
  *(uint2*)(dst + i) = o;
}

// wts: m-major [m][9] (gemm2 epilogue) AND expert-major wtsE [9][m] (gemm1).
__global__ void wts_k(const float* __restrict__ gp, const float* __restrict__ sg,
                      float* __restrict__ wts, float* __restrict__ wtsE) {
  int t = blockIdx.x * 256 + threadIdx.x;
  if (t >= Mm) return;
  float s = sg[t];
  float om = 1.0f - s;
#pragma unroll
  for (int e = 0; e < 8; ++e) {
    float v = om * gp[t * 8 + e];
    wts[t * 9 + e] = v;
    wtsE[(size_t)e * Mm + t] = v;
  }
  wts[t * 9 + 8] = s;
  wtsE[(size_t)8 * Mm + t] = s;
}

// Merged weight transposes:
//  bid < 9216 : W1 [D][F] f32 -> W1T [e][F][D] bf16
//  bid >= 9216: W2 [F][D] f32 -> W2T [D][9F]   bf16 (expert e at col base e*F)
__global__ void wt_k(const float* __restrict__ W1, const float* __restrict__ Ws1,
                     const float* __restrict__ W2, const float* __restrict__ Ws2,
                     unsigned short* __restrict__ W1T, unsigned short* __restrict__ W2T) {
  __shared__ float tile[32][33];
  const int tx = threadIdx.x, ty = threadIdx.y;
  int bid = blockIdx.x;
  if (bid < 9216) {
    const int e = bid >> 10;
    const int rem = bid & 1023;
    const float* src = (e < 8) ? (W1 + (size_t)e * Dm * Fm) : Ws1;
    const int c0 = (rem & 63) << 5;    // F
    const int r0 = (rem >> 6) << 5;    // D
#pragma unroll
    for (int j = ty; j < 32; j += 8) tile[j][tx] = src[(size_t)(r0 + j) * Fm + c0 + tx];
    __syncthreads();
    unsigned short* de = W1T + (size_t)e * Fm * Dm;
#pragma unroll
    for (int j = ty; j < 32; j += 8) de[(size_t)(c0 + j) * Dm + r0 + tx] = f2bf(tile[tx][j]);
  } else {
    bid -= 9216;
    const int e = bid >> 10;
    const int rem = bid & 1023;
    const float* src = (e < 8) ? (W2 + (size_t)e * Fm * Dm) : Ws2;
    const int c0 = (rem & 15) << 5;    // D
    const int r0 = (rem >> 4) << 5;    // F
#pragma unroll
    for (int j = ty; j < 32; j += 8) tile[j][tx] = src[(size_t)(r0 + j) * Dm + c0 + tx];
    __syncthreads();
#pragma unroll
    for (int j = ty; j < 32; j += 8)
      W2T[(size_t)(c0 + j) * KTOT + (size_t)e * Fm + r0 + tx] = f2bf(tile[tx][j]);
  }
}

// ---------- GEMM1 (persistent): Hs[m, el*F+f] = wtsE[eg,m] * gelu(X @ W1_eg + b1_eg)
// Grid fixed 512 (2 blocks/CU). Each block runs TPB = Gg*4 consecutive
// 128(M)x64(N) tiles through ONE continuous 3-buffer counted-vmcnt pipeline
// (global stage counter s = tile*8 + kstep). Next tile's loads stay in flight
// across the per-tile gelu epilogue (pure VALU + stores). Tile order:
// n fastest within a block's chunk (A-row L2 reuse); chunks XCD-swizzled.

__global__ __launch_bounds__(256)
void gemm1_k(const unsigned short* __restrict__ Xb,
             const unsigned short* __restrict__ W1T,
             const float* __restrict__ b1, const float* __restrict__ bs1,
             const float* __restrict__ wtsE,
             unsigned short* __restrict__ Hs,
             int gbase, int Gg, int ldH) {
  __shared__ __attribute__((aligned(16))) unsigned short As[3][128 * 64];
  __shared__ __attribute__((aligned(16))) unsigned short Bs[3][64 * 64];

  const int tid = threadIdx.x, l = tid & 63, w = tid >> 6;
  const int wr = w >> 1, wc = w & 1;            // wave tile 64(M) x 32(N)
  const int TPB = Gg << 2;                      // tiles per block
  const int NS = TPB << 3;                      // stages per block (8 per tile)
  const int cbase = ((blockIdx.x & 7) * 64 + (blockIdx.x >> 3)) * TPB;

  f32x4 acc[4][2];
  const f32x4 zz = {0.f, 0.f, 0.f, 0.f};
#pragma unroll
  for (int mi = 0; mi < 4; ++mi)
#pragma unroll
    for (int ni = 0; ni < 2; ++ni) acc[mi][ni] = zz;

  const int srow = tid >> 3;                    // 0..31
  const int sc = ((tid & 7) ^ (srow & 7)) << 3; // inverse-swizzled source col

  // Stage s2: tile T = cbase + (s2>>3), k-chunk (s2&7)*64. 6 gload_lds (4A+2B).
#define STAGEP(buf, s2)                                                          \
  {                                                                              \
    const int T_ = cbase + ((s2) >> 3);                                          \
    const int e_ = T_ >> 11;                                                     \
    const int rem_ = T_ & 2047;                                                  \
    const int tn_ = (rem_ & 31) << 6;                                            \
    const int tm_ = (rem_ >> 5) << 7;                                            \
    const int ks_ = ((s2) & 7) << 6;                                             \
    const unsigned short* BT_ = W1T + (size_t)(gbase + e_) * (Fm * Dm);          \
    _Pragma("unroll")                                                            \
    for (int i = 0; i < 4; ++i) {                                                \
      const int row = i * 32 + srow;                                             \
      gload_lds16(Xb + (size_t)(tm_ + row) * Dm + ks_ + sc,                      \
                  (char*)As[buf] + i * 4096 + tid * 16);                         \
    }                                                                            \
    _Pragma("unroll")                                                            \
    for (int i = 0; i < 2; ++i) {                                                \
      const int row = i * 32 + srow;                                             \
      gload_lds16(BT_ + (size_t)(tn_ + BPERM2(row)) * Dm + ks_ + sc,             \
                  (char*)Bs[buf] + i * 4096 + tid * 16);                         \
    }                                                                            \
  }

  STAGEP(0, 0);
  STAGEP(1, 1);

  // gelu(v)*wt folded constants: g = v*rcp(1+exp2(v*(A + B*v^2)))
  const float Ac = -2.3022120f;    // -2*0.7978845608*log2(e)
  const float Bc = -0.10294341f;   // Ac*0.044715

  int cur = 0;
#pragma unroll 1
  for (int j = 0; j < TPB; ++j) {
    // Current-tile coords + epilogue preload (5 VMEM loads, pinned here by the
    // memory-clobber barrier asm below; complete long before the epilogue).
    const int T = cbase + j;
    const int el = T >> 11;
    const int eg = gbase + el;
    const int rem = T & 2047;
    const int tnj = (rem & 31) << 6;
    const int tmj = (rem >> 5) << 7;
    const float* bias = (eg < 8) ? (b1 + (size_t)eg * Fm) : bs1;
    const int row0 = tmj + wr * 64 + ((l >> 4) << 2);
    const int col0 = tnj + wc * 32 + ((l & 15) << 1);   // 2 contiguous cols
    f32x4 wq[4];
#pragma unroll
    for (int mi = 0; mi < 4; ++mi)
      wq[mi] = *(const f32x4*)(wtsE + (size_t)eg * Mm + row0 + mi * 16);
    const float2 bv = *(const float2*)(bias + col0);

#pragma unroll 1
    for (int t = 0; t < 8; ++t) {
      const int s = (j << 3) + t;
      if (s + 1 < NS) { WAIT_BARRIER(6); } else { WAIT_BARRIER(0); }
      __builtin_amdgcn_sched_barrier(0);
      if (s + 2 < NS) {
        int nb = cur + 2; if (nb >= 3) nb -= 3;
        STAGEP(nb, s + 2);
      }
#pragma unroll
      for (int kk = 0; kk < 2; ++kk) {
        const int kbx = (kk * 64 + ((l >> 4) << 4)) ^ ((l & 7) << 4);
        short8 af[4], bfr[2];
#pragma unroll
        for (int mi = 0; mi < 4; ++mi)
          af[mi] = *(const short8*)((const char*)As[cur] + ((wr * 64 + mi * 16 + (l & 15)) << 7) + kbx);
#pragma unroll
        for (int ni = 0; ni < 2; ++ni)
          bfr[ni] = *(const short8*)((const char*)Bs[cur] + ((wc * 32 + ni * 16 + (l & 15)) << 7) + kbx);
#pragma unroll
        for (int mi = 0; mi < 4; ++mi)
#pragma unroll
          for (int ni = 0; ni < 2; ++ni)
            acc[mi][ni] = mfma16(af[mi], bfr[ni], acc[mi][ni]);
      }
      cur = (cur + 1 == 3) ? 0 : cur + 1;
    }

    // Per-tile epilogue (regs + global only, no LDS): overlaps in-flight loads.
    const size_t hb = (size_t)el * Fm;
#pragma unroll
    for (int mi = 0; mi < 4; ++mi) {
#pragma unroll
      for (int r = 0; r < 4; ++r) {
        const int rr = row0 + mi * 16 + r;
        const float wt = wq[mi][r];
        float g0, g1;
        {
          const float v = acc[mi][0][r] + bv.x;
          const float t2 = v * fmaf(Bc, v * v, Ac);
          g0 = wt * v * fast_rcp(1.0f + fast_exp2(t2));
        }
        {
          const float v = acc[mi][1][r] + bv.y;
          const float t2 = v * fmaf(Bc, v * v, Ac);
          g1 = wt * v * fast_rcp(1.0f + fast_exp2(t2));
        }
        unsigned pk;
        asm("v_cvt_pk_bf16_f32 %0, %1, %2" : "=v"(pk) : "v"(g0), "v"(g1));
        *(unsigned*)(Hs + (size_t)rr * ldH + hb + col0) = pk;   // 2 bf16, 4B
        acc[mi][0][r] = 0.f;
        acc[mi][1][r] = 0.f;
      }
    }
  }
#undef STAGEP
}

// ---------- GEMM2: out[m,d] (+)= Hs[m,0:Kt] @ W2Tg[d,0:Kt]^T  (+ gated bias on g0)
// 128(M) x 64(N) tile, BK=64, 4 waves (64x32/wave), register acc over concat-K.
// 3-stage LDS pipeline with counted vmcnt (T4): 12 loads in flight, fused
// wait+barrier (no vmcnt(0) drain mid-loop). Grid 512 = 2 blocks/CU.
// B-columns permuted (BPERM2) so each thread's 2 output cols are contiguous.

__global__ __launch_bounds__(256)
void gemm2_k(const unsigned short* __restrict__ A, int lda,
             const unsigned short* __restrict__ BT, int ldb,
             float* __restrict__ out,
             const float* __restrict__ wts,
             const float* __restrict__ b2, const float* __restrict__ bs2,
             int Kt, int g0) {
  __shared__ __attribute__((aligned(16))) unsigned short As[3][128 * 64];
  __shared__ __attribute__((aligned(16))) unsigned short Bs[3][64 * 64];

  const int tid = threadIdx.x, l = tid & 63, w = tid >> 6;
  const int wr = w >> 1, wc = w & 1;            // wave tile 64(M) x 32(N)
  const int wg = (blockIdx.x & 7) * 64 + (blockIdx.x >> 3);
  const int gm = wg >> 6;                       // m-group
  const int sub = wg & 63;                      // 8m x 8n, n fastest
  const int tn = (sub & 7) << 6;
  const int tm = ((gm << 3) + (sub >> 3)) << 7;

  f32x4 acc[4][2];
  const f32x4 zz = {0.f, 0.f, 0.f, 0.f};
#pragma unroll
  for (int mi = 0; mi < 4; ++mi)
#pragma unroll
    for (int ni = 0; ni < 2; ++ni) acc[mi][ni] = zz;

  const int srow = tid >> 3;                    // 0..31
  const int sc = ((tid & 7) ^ (srow & 7)) << 3;

  // 6 gload_lds per STAGE (4 A + 2 B)
#define STAGE2(buf, ks)                                                          \
  {                                                                              \
    _Pragma("unroll")                                                            \
    for (int i = 0; i < 4; ++i) {                                                \
      const int row = i * 32 + srow;                                             \
      gload_lds16(A + (size_t)(tm + row) * lda + (ks) + sc,                      \
                  (char*)As[buf] + i * 4096 + tid * 16);                         \
    }                                                                            \
    _Pragma("unroll")                                                            \
    for (int i = 0; i < 2; ++i) {                                                \
      const int row = i * 32 + srow;                                             \
      gload_lds16(BT + (size_t)(tn + BPERM2(row)) * ldb + (ks) + sc,             \
                  (char*)Bs[buf] + i * 4096 + tid * 16);                         \
    }                                                                            \
  }

  const int NT = Kt >> 6;
  STAGE2(0, 0);
  STAGE2(1, 64);

#pragma unroll 1
  for (int t = 0; t < NT; ++t) {
    const int cur = t % 3;
    // stage t complete; stage t+1's 6 loads may remain in flight
    if (t + 1 < NT) { WAIT_BARRIER(6); }
    else            { WAIT_BARRIER(0); }
    __builtin_amdgcn_sched_barrier(0);
    if (t + 2 < NT) {
      const int nb = (t + 2) % 3;
      STAGE2(nb, (t + 2) << 6);
    }
#pragma unroll
    for (int kk = 0; kk < 2; ++kk) {
      const int kbx = (kk * 64 + ((l >> 4) << 4)) ^ ((l & 7) << 4);
      short8 af[4], bfr[2];
#pragma unroll
      for (int mi = 0; mi < 4; ++mi)
        af[mi] = *(const short8*)((const char*)As[cur] + ((wr * 64 + mi * 16 + (l & 15)) << 7) + kbx);
#pragma unroll
      for (int ni = 0; ni < 2; ++ni)
        bfr[ni] = *(const short8*)((const char*)Bs[cur] + ((wc * 32 + ni * 16 + (l & 15)) << 7) + kbx);
#pragma unroll
      for (int mi = 0; mi < 4; ++mi)
#pragma unroll
        for (int ni = 0; ni < 2; ++ni)
          acc[mi][ni] = mfma16(af[mi], bfr[ni], acc[mi][ni]);
    }
  }
#undef STAGE2

  const int row0 = tm + wr * 64 + ((l >> 4) << 2);
  const int col0 = tn + wc * 32 + ((l & 15) << 1);   // 2 contiguous output cols

  if (g0) {
    float bcol[2][9];
#pragma unroll
    for (int ni = 0; ni < 2; ++ni) {
      const int c = col0 + ni;
#pragma unroll
      for (int e = 0; e < 8; ++e) bcol[ni][e] = b2[(e << 9) + c];
      bcol[ni][8] = bs2[c];
    }
#pragma unroll
    for (int mi = 0; mi < 4; ++mi)
#pragma unroll
      for (int r = 0; r < 4; ++r) {
        const int rr = row0 + mi * 16 + r;
        const float* wrow = wts + (size_t)rr * 9;
        float b0 = 0.f, b1v = 0.f;
#pragma unroll
        for (int e = 0; e < 9; ++e) { b0 += wrow[e] * bcol[0][e]; b1v += wrow[e] * bcol[1][e]; }
        float2 o;
        o.x = acc[mi][0][r] + b0;
        o.y = acc[mi][1][r] + b1v;
        *(float2*)(out + (size_t)rr * Dm + col0) = o;
      }
  } else {
#pragma unroll
    for (int mi = 0; mi < 4; ++mi)
#pragma unroll
      for (int r = 0; r < 4; ++r) {
        float* p = out + (size_t)(row0 + mi * 16 + r) * Dm + col0;
        float2 o = *(float2*)p;
        o.x += acc[mi][0][r];
        o.y += acc[mi][1][r];
        *(float2*)p = o;
      }
  }
}

// ---------- launch ----------

extern "C" void kernel_launch(void* const* d_in, const int* in_sizes, int n_in,
                              void* d_out, int out_size, void* d_ws, size_t ws_size,
                              hipStream_t stream) {
  const float* x   = (const float*)d_in[0];
  const float* gp  = (const float*)d_in[1];
  const float* sg  = (const float*)d_in[2];
  const float* W1  = (const float*)d_in[3];
  const float* b1  = (const float*)d_in[4];
  const float* W2  = (const float*)d_in[5];
  const float* b2  = (const float*)d_in[6];
  const float* Ws1 = (const float*)d_in[7];
  const float* bs1 = (const float*)d_in[8];
  const float* Ws2 = (const float*)d_in[9];
  const float* bs2 = (const float*)d_in[10];
  float* out = (float*)d_out;

  const size_t szXb   = (size_t)Mm * Dm * 2;        //  8,388,608
  const size_t szWts  = (size_t)Mm * 9 * 4;         //    294,912
  const size_t szWtsE = (size_t)Mm * 9 * 4;         //    294,912
  const size_t szW1T  = (size_t)9 * Fm * Dm * 2;    // 18,874,368
  const size_t szW2T  = (size_t)9 * Fm * Dm * 2;    // 18,874,368
  const size_t base   = szXb + szWts + szWtsE + szW1T + szW2T;

  int G;
  if      (ws_size >= base + (size_t)Mm * 9 * Fm * 2) G = 9;
  else if (ws_size >= base + (size_t)Mm * 3 * Fm * 2) G = 3;
  else if (ws_size >= base + (size_t)Mm * 2 * Fm * 2) G = 2;
  else if (ws_size >= base + (size_t)Mm * 1 * Fm * 2) G = 1;
  else return;

  char* ws = (char*)d_ws;
  unsigned short* Xb   = (unsigned short*)(ws);
  float*          wts  = (float*)(ws + szXb);
  float*          wtsE = (float*)(ws + szXb + szWts);
  unsigned short* W1T  = (unsigned short*)(ws + szXb + szWts + szWtsE);
  unsigned short* W2T  = (unsigned short*)(ws + szXb + szWts + szWtsE + szW1T);
  unsigned short* Hs   = (unsigned short*)(ws + base);
  const int ldH = G * Fm;

  cvtx_k<<<dim3((Mm * Dm) / 1024), dim3(256), 0, stream>>>(x, Xb, Mm * Dm);
  wts_k<<<dim3(Mm / 256), dim3(256), 0, stream>>>(gp, sg, wts, wtsE);
  wt_k<<<dim3(2 * 9 * 1024), dim3(32, 8), 0, stream>>>(W1, Ws1, W2, Ws2, W1T, W2T);

  for (int gb = 0; gb < 9; gb += G) {
    const int Gg = (9 - gb < G) ? (9 - gb) : G;
    gemm1_k<<<dim3(512), dim3(256), 0, stream>>>(
        Xb, W1T, b1, bs1, wtsE, Hs, gb, Gg, ldH);
    gemm2_k<<<dim3(512), dim3(256), 0, stream>>>(
        Hs, ldH, W2T + (size_t)gb * Fm, KTOT, out, wts, b2, bs2, Gg * Fm, gb == 0 ? 1 : 0);
  }
}

// Round 5
// 457.136 us; speedup vs baseline: 1.0628x; 1.0628x over previous
//
#include <hip/hip_runtime.h>

#define Dm 512
#define Fm 2048
#define Mm 8192    // B*S tokens
#define KTOT 18432 // 9*Fm

typedef __attribute__((ext_vector_type(8))) short short8;
typedef __attribute__((ext_vector_type(4))) float f32x4;

// ---------- helpers ----------

__device__ __forceinline__ unsigned short f2bf(float f) {
  unsigned u = __builtin_bit_cast(unsigned, f);
  u = (u + 0x7FFFu + ((u >> 16) & 1u)) >> 16;
  return (unsigned short)u;
}

__device__ __forceinline__ float fast_exp2(float x) {
  float r; asm("v_exp_f32 %0, %1" : "=v"(r) : "v"(x)); return r;
}
__device__ __forceinline__ float fast_rcp(float x) {
  float r; asm("v_rcp_f32 %0, %1" : "=v"(r) : "v"(x)); return r;
}

__device__ __forceinline__ void gload_lds16(const void* g, void* lp) {
  __builtin_amdgcn_global_load_lds(
      (const __attribute__((address_space(1))) void*)(unsigned long long)(g),
      (__attribute__((address_space(3))) void*)(unsigned)(unsigned long long)(lp),
      16, 0, 0);
}

__device__ __forceinline__ f32x4 mfma16(short8 a, short8 b, f32x4 c) {
  asm("v_mfma_f32_16x16x32_bf16 %0, %1, %2, %0" : "+v"(c) : "v"(a), "v"(b));
  return c;
}

// Fused wait+barrier as ONE memory-clobber asm: a full compiler memory fence.
// vmcnt(6) is placement-independent-safe: every stage has >=6 VMEM ops issued
// after it before its wait, so "all but newest 6 complete" always covers the
// stage being consumed (extra epilogue VMEM only makes the wait stricter).
#define WAIT_BARRIER(n) asm volatile("s_waitcnt vmcnt(" #n ")\n\ts_barrier" ::: "memory")

// B row permutation within each 32-row block: LDS row (32a + 16n + c) holds
// global col (32a + 2c + n)  => frag ni, lane c -> global col 2c + ni
// (thread's 2 output columns contiguous).
#define BPERM2(r) (((r) & 32) | (((r) & 15) << 1) | (((r) >> 4) & 1))

// ---------- prep kernels ----------

__global__ void cvtx_k(const float* __restrict__ src, unsigned short* __restrict__ dst, int n) {
  int i = (blockIdx.x * 256 + threadIdx.x) * 4;
  if (i >= n) return;
  const float4 v = *(const float4*)(src + i);
  unsigned a = (unsigned)f2bf(v.x) | ((unsigned)f2bf(v.y) << 16);
  unsigned b = (unsigned)f2bf(v.z) | ((unsigned)f2bf(v.w) << 16);
  uint2 o; o.x = a; o.y = b;
  *(uint2*)(dst + i) = o;
}

// wts: m-major [m][9] (gemm2 epilogue) AND expert-major wtsE [9][m] (gemm1).
__global__ void wts_k(const float* __restrict__ gp, const float* __restrict__ sg,
                      float* __restrict__ wts, float* __restrict__ wtsE) {
  int t = blockIdx.x * 256 + threadIdx.x;
  if (t >= Mm) return;
  float s = sg[t];
  float om = 1.0f - s;
#pragma unroll
  for (int e = 0; e < 8; ++e) {
    float v = om * gp[t * 8 + e];
    wts[t * 9 + e] = v;
    wtsE[(size_t)e * Mm + t] = v;
  }
  wts[t * 9 + 8] = s;
  wtsE[(size_t)8 * Mm + t] = s;
}

// Merged weight transposes:
//  bid < 9216 : W1 [D][F] f32 -> W1T [e][F][D] bf16
//  bid >= 9216: W2 [F][D] f32 -> W2T [D][9F]   bf16 (expert e at col base e*F)
__global__ void wt_k(const float* __restrict__ W1, const float* __restrict__ Ws1,
                     const float* __restrict__ W2, const float* __restrict__ Ws2,
                     unsigned short* __restrict__ W1T, unsigned short* __restrict__ W2T) {
  __shared__ float tile[32][33];
  const int tx = threadIdx.x, ty = threadIdx.y;
  int bid = blockIdx.x;
  if (bid < 9216) {
    const int e = bid >> 10;
    const int rem = bid & 1023;
    const float* src = (e < 8) ? (W1 + (size_t)e * Dm * Fm) : Ws1;
    const int c0 = (rem & 63) << 5;    // F
    const int r0 = (rem >> 6) << 5;    // D
#pragma unroll
    for (int j = ty; j < 32; j += 8) tile[j][tx] = src[(size_t)(r0 + j) * Fm + c0 + tx];
    __syncthreads();
    unsigned short* de = W1T + (size_t)e * Fm * Dm;
#pragma unroll
    for (int j = ty; j < 32; j += 8) de[(size_t)(c0 + j) * Dm + r0 + tx] = f2bf(tile[tx][j]);
  } else {
    bid -= 9216;
    const int e = bid >> 10;
    const int rem = bid & 1023;
    const float* src = (e < 8) ? (W2 + (size_t)e * Fm * Dm) : Ws2;
    const int c0 = (rem & 15) << 5;    // D
    const int r0 = (rem >> 4) << 5;    // F
#pragma unroll
    for (int j = ty; j < 32; j += 8) tile[j][tx] = src[(size_t)(r0 + j) * Dm + c0 + tx];
    __syncthreads();
#pragma unroll
    for (int j = ty; j < 32; j += 8)
      W2T[(size_t)(c0 + j) * KTOT + (size_t)e * Fm + r0 + tx] = f2bf(tile[tx][j]);
  }
}

// ---------- GEMM1 (persistent, STRIDED): Hs = wtsE * gelu(X @ W1 + b1) ----------
// Grid fixed 512 (2 blocks/CU). Block b handles virtual tiles v = j*512 + b,
// j = 0..TPB-1, mapped through the XCD-bijective swizzle of a virtual Gg*2048
// grid -> at every step the co-resident 512 blocks cover a CONSECUTIVE window
// of tiles (per XCD: 2 m-panels x full expert B => fits 4MB XCD L2), restoring
// round-3 locality. One continuous 3-buffer counted-vmcnt pipeline crosses
// tile boundaries without draining (long-NT like gemm2). 128(M)x64(N) tiles,
// BK=64, 4 waves (64x32/wave).

__global__ __launch_bounds__(256)
void gemm1_k(const unsigned short* __restrict__ Xb,
             const unsigned short* __restrict__ W1T,
             const float* __restrict__ b1, const float* __restrict__ bs1,
             const float* __restrict__ wtsE,
             unsigned short* __restrict__ Hs,
             int gbase, int Gg, int ldH) {
  __shared__ __attribute__((aligned(16))) unsigned short As[3][128 * 64];
  __shared__ __attribute__((aligned(16))) unsigned short Bs[3][64 * 64];

  const int tid = threadIdx.x, l = tid & 63, w = tid >> 6;
  const int wr = w >> 1, wc = w & 1;            // wave tile 64(M) x 32(N)
  const int VG = Gg << 11;                      // virtual grid (Gg*2048 tiles)
  const int TPB = VG >> 9;                      // tiles per block (VG/512)
  const int NS = TPB << 3;                      // stages per block (8 per tile)
  const int b = blockIdx.x;

  // virtual tile v -> (expert, tm, tn): XCD-bijective swizzle + n-fastest
#define TILE_COORDS(v, el_, tm_, tn_)                                            \
  const int wg_ = ((v) & 7) * (VG >> 3) + ((v) >> 3);                            \
  const int el_ = wg_ >> 11;                                                     \
  const int rem_ = wg_ & 2047;                                                   \
  const int tn_ = (rem_ & 31) << 6;                                              \
  const int tm_ = (rem_ >> 5) << 7;

  f32x4 acc[4][2];
  const f32x4 zz = {0.f, 0.f, 0.f, 0.f};
#pragma unroll
  for (int mi = 0; mi < 4; ++mi)
#pragma unroll
    for (int ni = 0; ni < 2; ++ni) acc[mi][ni] = zz;

  const int srow = tid >> 3;                    // 0..31
  const int sc = ((tid & 7) ^ (srow & 7)) << 3; // inverse-swizzled source col

  // Stage s2: tile j2 = s2>>3 (strided), k-chunk (s2&7)*64. 6 gload_lds (4A+2B).
#define STAGEP(buf, s2)                                                          \
  {                                                                              \
    const int v_ = (((s2) >> 3) << 9) + b;                                       \
    TILE_COORDS(v_, se_, stm_, stn_)                                             \
    const int ks_ = ((s2) & 7) << 6;                                             \
    const unsigned short* BT_ = W1T + (size_t)(gbase + se_) * (Fm * Dm);         \
    _Pragma("unroll")                                                            \
    for (int i = 0; i < 4; ++i) {                                                \
      const int row = i * 32 + srow;                                             \
      gload_lds16(Xb + (size_t)(stm_ + row) * Dm + ks_ + sc,                     \
                  (char*)As[buf] + i * 4096 + tid * 16);                         \
    }                                                                            \
    _Pragma("unroll")                                                            \
    for (int i = 0; i < 2; ++i) {                                                \
      const int row = i * 32 + srow;                                             \
      gload_lds16(BT_ + (size_t)(stn_ + BPERM2(row)) * Dm + ks_ + sc,            \
                  (char*)Bs[buf] + i * 4096 + tid * 16);                         \
    }                                                                            \
  }

  STAGEP(0, 0);
  STAGEP(1, 1);

  // gelu(v)*wt folded constants: g = v*rcp(1+exp2(v*(A + B*v^2)))
  const float Ac = -2.3022120f;    // -2*0.7978845608*log2(e)
  const float Bc = -0.10294341f;   // Ac*0.044715

  int cur = 0;
#pragma unroll 1
  for (int j = 0; j < TPB; ++j) {
    // Current-tile coords + epilogue preload (5 VMEM loads; complete long
    // before the epilogue; they only make the counted waits stricter).
    const int v = (j << 9) + b;
    TILE_COORDS(v, el, tmj, tnj)
    const int eg = gbase + el;
    const float* bias = (eg < 8) ? (b1 + (size_t)eg * Fm) : bs1;
    const int row0 = tmj + wr * 64 + ((l >> 4) << 2);
    const int col0 = tnj + wc * 32 + ((l & 15) << 1);   // 2 contiguous cols
    f32x4 wq[4];
#pragma unroll
    for (int mi = 0; mi < 4; ++mi)
      wq[mi] = *(const f32x4*)(wtsE + (size_t)eg * Mm + row0 + mi * 16);
    const float2 bv = *(const float2*)(bias + col0);

#pragma unroll 1
    for (int t = 0; t < 8; ++t) {
      const int s = (j << 3) + t;
      if (s + 1 < NS) { WAIT_BARRIER(6); } else { WAIT_BARRIER(0); }
      __builtin_amdgcn_sched_barrier(0);
      if (s + 2 < NS) {
        int nb = cur + 2; if (nb >= 3) nb -= 3;
        STAGEP(nb, s + 2);
      }
#pragma unroll
      for (int kk = 0; kk < 2; ++kk) {
        const int kbx = (kk * 64 + ((l >> 4) << 4)) ^ ((l & 7) << 4);
        short8 af[4], bfr[2];
#pragma unroll
        for (int mi = 0; mi < 4; ++mi)
          af[mi] = *(const short8*)((const char*)As[cur] + ((wr * 64 + mi * 16 + (l & 15)) << 7) + kbx);
#pragma unroll
        for (int ni = 0; ni < 2; ++ni)
          bfr[ni] = *(const short8*)((const char*)Bs[cur] + ((wc * 32 + ni * 16 + (l & 15)) << 7) + kbx);
#pragma unroll
        for (int mi = 0; mi < 4; ++mi)
#pragma unroll
          for (int ni = 0; ni < 2; ++ni)
            acc[mi][ni] = mfma16(af[mi], bfr[ni], acc[mi][ni]);
      }
      cur = (cur + 1 == 3) ? 0 : cur + 1;
    }

    // Per-tile epilogue (regs + global only, no LDS): overlaps in-flight loads.
    const size_t hb = (size_t)el * Fm;
#pragma unroll
    for (int mi = 0; mi < 4; ++mi) {
#pragma unroll
      for (int r = 0; r < 4; ++r) {
        const int rr = row0 + mi * 16 + r;
        const float wt = wq[mi][r];
        float g0, g1;
        {
          const float v2 = acc[mi][0][r] + bv.x;
          const float t2 = v2 * fmaf(Bc, v2 * v2, Ac);
          g0 = wt * v2 * fast_rcp(1.0f + fast_exp2(t2));
        }
        {
          const float v2 = acc[mi][1][r] + bv.y;
          const float t2 = v2 * fmaf(Bc, v2 * v2, Ac);
          g1 = wt * v2 * fast_rcp(1.0f + fast_exp2(t2));
        }
        unsigned pk;
        asm("v_cvt_pk_bf16_f32 %0, %1, %2" : "=v"(pk) : "v"(g0), "v"(g1));
        *(unsigned*)(Hs + (size_t)rr * ldH + hb + col0) = pk;   // 2 bf16, 4B
        acc[mi][0][r] = 0.f;
        acc[mi][1][r] = 0.f;
      }
    }
  }
#undef STAGEP
#undef TILE_COORDS
}

// ---------- GEMM2: out[m,d] (+)= Hs[m,0:Kt] @ W2Tg[d,0:Kt]^T  (+ gated bias on g0)
// 128(M) x 64(N) tile, BK=64, 4 waves (64x32/wave), register acc over concat-K.
// 3-stage LDS pipeline with counted vmcnt (T4): 12 loads in flight, fused
// wait+barrier (no vmcnt(0) drain mid-loop). Grid 512 = 2 blocks/CU.
// B-columns permuted (BPERM2) so each thread's 2 output cols are contiguous.

__global__ __launch_bounds__(256)
void gemm2_k(const unsigned short* __restrict__ A, int lda,
             const unsigned short* __restrict__ BT, int ldb,
             float* __restrict__ out,
             const float* __restrict__ wts,
             const float* __restrict__ b2, const float* __restrict__ bs2,
             int Kt, int g0) {
  __shared__ __attribute__((aligned(16))) unsigned short As[3][128 * 64];
  __shared__ __attribute__((aligned(16))) unsigned short Bs[3][64 * 64];

  const int tid = threadIdx.x, l = tid & 63, w = tid >> 6;
  const int wr = w >> 1, wc = w & 1;            // wave tile 64(M) x 32(N)
  const int wg = (blockIdx.x & 7) * 64 + (blockIdx.x >> 3);
  const int gm = wg >> 6;                       // m-group
  const int sub = wg & 63;                      // 8m x 8n, n fastest
  const int tn = (sub & 7) << 6;
  const int tm = ((gm << 3) + (sub >> 3)) << 7;

  f32x4 acc[4][2];
  const f32x4 zz = {0.f, 0.f, 0.f, 0.f};
#pragma unroll
  for (int mi = 0; mi < 4; ++mi)
#pragma unroll
    for (int ni = 0; ni < 2; ++ni) acc[mi][ni] = zz;

  const int srow = tid >> 3;                    // 0..31
  const int sc = ((tid & 7) ^ (srow & 7)) << 3;

  // 6 gload_lds per STAGE (4 A + 2 B)
#define STAGE2(buf, ks)                                                          \
  {                                                                              \
    _Pragma("unroll")                                                            \
    for (int i = 0; i < 4; ++i) {                                                \
      const int row = i * 32 + srow;                                             \
      gload_lds16(A + (size_t)(tm + row) * lda + (ks) + sc,                      \
                  (char*)As[buf] + i * 4096 + tid * 16);                         \
    }                                                                            \
    _Pragma("unroll")                                                            \
    for (int i = 0; i < 2; ++i) {                                                \
      const int row = i * 32 + srow;                                             \
      gload_lds16(BT + (size_t)(tn + BPERM2(row)) * ldb + (ks) + sc,             \
                  (char*)Bs[buf] + i * 4096 + tid * 16);                         \
    }                                                                            \
  }

  const int NT = Kt >> 6;
  STAGE2(0, 0);
  STAGE2(1, 64);

#pragma unroll 1
  for (int t = 0; t < NT; ++t) {
    const int cur = t % 3;
    // stage t complete; stage t+1's 6 loads may remain in flight
    if (t + 1 < NT) { WAIT_BARRIER(6); }
    else            { WAIT_BARRIER(0); }
    __builtin_amdgcn_sched_barrier(0);
    if (t + 2 < NT) {
      const int nb = (t + 2) % 3;
      STAGE2(nb, (t + 2) << 6);
    }
#pragma unroll
    for (int kk = 0; kk < 2; ++kk) {
      const int kbx = (kk * 64 + ((l >> 4) << 4)) ^ ((l & 7) << 4);
      short8 af[4], bfr[2];
#pragma unroll
      for (int mi = 0; mi < 4; ++mi)
        af[mi] = *(const short8*)((const char*)As[cur] + ((wr * 64 + mi * 16 + (l & 15)) << 7) + kbx);
#pragma unroll
      for (int ni = 0; ni < 2; ++ni)
        bfr[ni] = *(const short8*)((const char*)Bs[cur] + ((wc * 32 + ni * 16 + (l & 15)) << 7) + kbx);
#pragma unroll
      for (int mi = 0; mi < 4; ++mi)
#pragma unroll
        for (int ni = 0; ni < 2; ++ni)
          acc[mi][ni] = mfma16(af[mi], bfr[ni], acc[mi][ni]);
    }
  }
#undef STAGE2

  const int row0 = tm + wr * 64 + ((l >> 4) << 2);
  const int col0 = tn + wc * 32 + ((l & 15) << 1);   // 2 contiguous output cols

  if (g0) {
    float bcol[2][9];
#pragma unroll
    for (int ni = 0; ni < 2; ++ni) {
      const int c = col0 + ni;
#pragma unroll
      for (int e = 0; e < 8; ++e) bcol[ni][e] = b2[(e << 9) + c];
      bcol[ni][8] = bs2[c];
    }
#pragma unroll
    for (int mi = 0; mi < 4; ++mi)
#pragma unroll
      for (int r = 0; r < 4; ++r) {
        const int rr = row0 + mi * 16 + r;
        const float* wrow = wts + (size_t)rr * 9;
        float b0 = 0.f, b1v = 0.f;
#pragma unroll
        for (int e = 0; e < 9; ++e) { b0 += wrow[e] * bcol[0][e]; b1v += wrow[e] * bcol[1][e]; }
        float2 o;
        o.x = acc[mi][0][r] + b0;
        o.y = acc[mi][1][r] + b1v;
        *(float2*)(out + (size_t)rr * Dm + col0) = o;
      }
  } else {
#pragma unroll
    for (int mi = 0; mi < 4; ++mi)
#pragma unroll
      for (int r = 0; r < 4; ++r) {
        float* p = out + (size_t)(row0 + mi * 16 + r) * Dm + col0;
        float2 o = *(float2*)p;
        o.x += acc[mi][0][r];
        o.y += acc[mi][1][r];
        *(float2*)p = o;
      }
  }
}

// ---------- launch ----------

extern "C" void kernel_launch(void* const* d_in, const int* in_sizes, int n_in,
                              void* d_out, int out_size, void* d_ws, size_t ws_size,
                              hipStream_t stream) {
  const float* x   = (const float*)d_in[0];
  const float* gp  = (const float*)d_in[1];
  const float* sg  = (const float*)d_in[2];
  const float* W1  = (const float*)d_in[3];
  const float* b1  = (const float*)d_in[4];
  const float* W2  = (const float*)d_in[5];
  const float* b2  = (const float*)d_in[6];
  const float* Ws1 = (const float*)d_in[7];
  const float* bs1 = (const float*)d_in[8];
  const float* Ws2 = (const float*)d_in[9];
  const float* bs2 = (const float*)d_in[10];
  float* out = (float*)d_out;

  const size_t szXb   = (size_t)Mm * Dm * 2;        //  8,388,608
  const size_t szWts  = (size_t)Mm * 9 * 4;         //    294,912
  const size_t szWtsE = (size_t)Mm * 9 * 4;         //    294,912
  const size_t szW1T  = (size_t)9 * Fm * Dm * 2;    // 18,874,368
  const size_t szW2T  = (size_t)9 * Fm * Dm * 2;    // 18,874,368
  const size_t base   = szXb + szWts + szWtsE + szW1T + szW2T;

  int G;
  if      (ws_size >= base + (size_t)Mm * 9 * Fm * 2) G = 9;
  else if (ws_size >= base + (size_t)Mm * 3 * Fm * 2) G = 3;
  else if (ws_size >= base + (size_t)Mm * 2 * Fm * 2) G = 2;
  else if (ws_size >= base + (size_t)Mm * 1 * Fm * 2) G = 1;
  else return;

  char* ws = (char*)d_ws;
  unsigned short* Xb   = (unsigned short*)(ws);
  float*          wts  = (float*)(ws + szXb);
  float*          wtsE = (float*)(ws + szXb + szWts);
  unsigned short* W1T  = (unsigned short*)(ws + szXb + szWts + szWtsE);
  unsigned short* W2T  = (unsigned short*)(ws + szXb + szWts + szWtsE + szW1T);
  unsigned short* Hs   = (unsigned short*)(ws + base);
  const int ldH = G * Fm;

  cvtx_k<<<dim3((Mm * Dm) / 1024), dim3(256), 0, stream>>>(x, Xb, Mm * Dm);
  wts_k<<<dim3(Mm / 256), dim3(256), 0, stream>>>(gp, sg, wts, wtsE);
  wt_k<<<dim3(2 * 9 * 1024), dim3(32, 8), 0, stream>>>(W1, Ws1, W2, Ws2, W1T, W2T);

  for (int gb = 0; gb < 9; gb += G) {
    const int Gg = (9 - gb < G) ? (9 - gb) : G;
    gemm1_k<<<dim3(512), dim3(256), 0, stream>>>(
        Xb, W1T, b1, bs1, wtsE, Hs, gb, Gg, ldH);
    gemm2_k<<<dim3(512), dim3(256), 0, stream>>>(
        Hs, ldH, W2T + (size_t)gb * Fm, KTOT, out, wts, b2, bs2, Gg * Fm, gb == 0 ? 1 : 0);
  }
}

// Round 6
// 443.512 us; speedup vs baseline: 1.0954x; 1.0307x over previous
//
#include <hip/hip_runtime.h>

#define Dm 512
#define Fm 2048
#define Mm 8192    // B*S tokens
#define KTOT 18432 // 9*Fm

typedef __attribute__((ext_vector_type(8))) short short8;
typedef __attribute__((ext_vector_type(4))) float f32x4;

// ---------- helpers ----------

__device__ __forceinline__ unsigned short f2bf(float f) {
  unsigned u = __builtin_bit_cast(unsigned, f);
  u = (u + 0x7FFFu + ((u >> 16) & 1u)) >> 16;
  return (unsigned short)u;
}

__device__ __forceinline__ float fast_exp2(float x) {
  float r; asm("v_exp_f32 %0, %1" : "=v"(r) : "v"(x)); return r;
}
__device__ __forceinline__ float fast_rcp(float x) {
  float r; asm("v_rcp_f32 %0, %1" : "=v"(r) : "v"(x)); return r;
}

__device__ __forceinline__ void gload_lds16(const void* g, void* lp) {
  __builtin_amdgcn_global_load_lds(
      (const __attribute__((address_space(1))) void*)(unsigned long long)(g),
      (__attribute__((address_space(3))) void*)(unsigned)(unsigned long long)(lp),
      16, 0, 0);
}

__device__ __forceinline__ f32x4 mfma16(short8 a, short8 b, f32x4 c) {
  asm("v_mfma_f32_16x16x32_bf16 %0, %1, %2, %0" : "+v"(c) : "v"(a), "v"(b));
  return c;
}

// Fused wait+barrier as ONE memory-clobber asm: a full compiler memory fence.
// Counted vmcnt is placement-independent-safe: every waited-on stage has the
// counted number of VMEM ops issued after it.
#define WAIT_BARRIER(n) asm volatile("s_waitcnt vmcnt(" #n ")\n\ts_barrier" ::: "memory")

// B row permutation within each 64-row block: LDS row (64a + 16n + c) holds
// global col (64a + 4c + n)  => frag ni, lane c -> global col 4c + ni
// (thread's 4 output columns contiguous).
#define BPERM1(r) (((r) & 64) | (((r) & 15) << 2) | (((r) >> 4) & 3))

// B row permutation within each 32-row block (gemm2, 64-wide N tiles):
// LDS row (32a + 16n + c) holds global col (32a + 2c + n).
#define BPERM2(r) (((r) & 32) | (((r) & 15) << 1) | (((r) >> 4) & 1))

// ---------- prep kernels ----------

__global__ void cvtx_k(const float* __restrict__ src, unsigned short* __restrict__ dst, int n) {
  int i = (blockIdx.x * 256 + threadIdx.x) * 4;
  if (i >= n) return;
  const float4 v = *(const float4*)(src + i);
  unsigned a = (unsigned)f2bf(v.x) | ((unsigned)f2bf(v.y) << 16);
  unsigned b = (unsigned)f2bf(v.z) | ((unsigned)f2bf(v.w) << 16);
  uint2 o; o.x = a; o.y = b;
  *(uint2*)(dst + i) = o;
}

__global__ void wts_k(const float* __restrict__ gp, const float* __restrict__ sg,
                      float* __restrict__ wts) {
  int t = blockIdx.x * 256 + threadIdx.x;
  if (t >= Mm) return;
  float s = sg[t];
  float om = 1.0f - s;
#pragma unroll
  for (int e = 0; e < 8; ++e) wts[t * 9 + e] = om * gp[t * 8 + e];
  wts[t * 9 + 8] = s;
}

// Merged weight transposes:
//  bid < 9216 : W1 [D][F] f32 -> W1T [e][F][D] bf16
//  bid >= 9216: W2 [F][D] f32 -> W2T [D][9F]   bf16 (expert e at col base e*F)
__global__ void wt_k(const float* __restrict__ W1, const float* __restrict__ Ws1,
                     const float* __restrict__ W2, const float* __restrict__ Ws2,
                     unsigned short* __restrict__ W1T, unsigned short* __restrict__ W2T) {
  __shared__ float tile[32][33];
  const int tx = threadIdx.x, ty = threadIdx.y;
  int bid = blockIdx.x;
  if (bid < 9216) {
    const int e = bid >> 10;
    const int rem = bid & 1023;
    const float* src = (e < 8) ? (W1 + (size_t)e * Dm * Fm) : Ws1;
    const int c0 = (rem & 63) << 5;    // F
    const int r0 = (rem >> 6) << 5;    // D
#pragma unroll
    for (int j = ty; j < 32; j += 8) tile[j][tx] = src[(size_t)(r0 + j) * Fm + c0 + tx];
    __syncthreads();
    unsigned short* de = W1T + (size_t)e * Fm * Dm;
#pragma unroll
    for (int j = ty; j < 32; j += 8) de[(size_t)(c0 + j) * Dm + r0 + tx] = f2bf(tile[tx][j]);
  } else {
    bid -= 9216;
    const int e = bid >> 10;
    const int rem = bid & 1023;
    const float* src = (e < 8) ? (W2 + (size_t)e * Fm * Dm) : Ws2;
    const int c0 = (rem & 15) << 5;    // D
    const int r0 = (rem >> 4) << 5;    // F
#pragma unroll
    for (int j = ty; j < 32; j += 8) tile[j][tx] = src[(size_t)(r0 + j) * Dm + c0 + tx];
    __syncthreads();
#pragma unroll
    for (int j = ty; j < 32; j += 8)
      W2T[(size_t)(c0 + j) * KTOT + (size_t)e * Fm + r0 + tx] = f2bf(tile[tx][j]);
  }
}

// ---------- GEMM1: Hs[m, el*F+f] = wts[m,eg] * gelu(X @ W1_eg + b1_eg) ----------
// 128x128 tile, 4 waves (wave tile 64x64), round-3 coords/epilogue. K-loop is a
// 4-slot ring of BK=32 half-buffers with counted vmcnt(4): 16 phases, each
// {vmcnt(4)+barrier -> stage phase p+2 (4 gloads) -> 8 ds_read_b128 ->
//  16 MFMA (setprio)}. Loads stay 2 phases in flight; no drain-to-0 mid-loop.
// LDS 64KB -> 2 blocks/CU. Rows are 64B (32 bf16); k-slot XOR swizzle
// slot=(l>>4)^(row&3), source pre-inverse-swizzled.

__global__ __launch_bounds__(256)
void gemm1_k(const unsigned short* __restrict__ Xb,
             const unsigned short* __restrict__ W1T,
             const float* __restrict__ b1, const float* __restrict__ bs1,
             const float* __restrict__ wts,
             unsigned short* __restrict__ Hs,
             int gbase, int Gg, int ldH) {
  __shared__ __attribute__((aligned(16))) unsigned short As[4][128 * 32];
  __shared__ __attribute__((aligned(16))) unsigned short Bs[4][128 * 32];

  const int tid = threadIdx.x, l = tid & 63, w = tid >> 6;
  const int wr = w >> 1, wc = w & 1;
  const int nwg = Gg << 10;
  const int wg = (blockIdx.x & 7) * (nwg >> 3) + (blockIdx.x >> 3);  // bijective (nwg%8==0)
  const int el = wg >> 10;
  const int rem = wg & 1023;
  const int grp = rem >> 7;          // 8 m-groups per expert
  const int sub = rem & 127;         // 8 m x 16 n, n fastest
  const int tn = (sub & 15) << 7;
  const int tm = ((grp << 3) + (sub >> 4)) << 7;
  const int eg = gbase + el;
  const unsigned short* BT = W1T + (size_t)eg * Fm * Dm;
  const float* bias = (eg < 8) ? (b1 + (size_t)eg * Fm) : bs1;

  f32x4 acc[4][4];
  const f32x4 zz = {0.f, 0.f, 0.f, 0.f};
#pragma unroll
  for (int mi = 0; mi < 4; ++mi)
#pragma unroll
    for (int ni = 0; ni < 4; ++ni) acc[mi][ni] = zz;

  // staging: thread -> LDS row R = i*64 + (tid>>2), 16B slot (tid&3);
  // LDS(R, s) holds global k-elems (s ^ (R&3))*8 .. +7  (inverse-swizzled src)
  const int srowL = tid >> 2;                       // 0..63
  const int selem = ((tid & 3) ^ (srowL & 3)) << 3; // element offset in 32-col row

  // 4 gload_lds per phase (2 A + 2 B), 8KB A-half + 8KB B-half
#define STAGE1(slot, p2)                                                        \
  {                                                                             \
    const int ks_ = (p2) << 5;                                                  \
    _Pragma("unroll")                                                           \
    for (int i = 0; i < 2; ++i) {                                               \
      const int R = i * 64 + srowL;                                             \
      gload_lds16(Xb + (size_t)(tm + R) * Dm + ks_ + selem,                     \
                  (char*)As[slot] + i * 4096 + tid * 16);                       \
      gload_lds16(BT + (size_t)(tn + BPERM1(R)) * Dm + ks_ + selem,             \
                  (char*)Bs[slot] + i * 4096 + tid * 16);                       \
    }                                                                           \
  }

  STAGE1(0, 0);
  STAGE1(1, 1);

  // swizzled 16B k-slot within a 64B row (row&3 == l&3 for all frag rows)
  const int kby = (((l >> 4) ^ (l & 3)) << 4);
  const int arow = ((wr << 6) + (l & 15)) << 6;   // byte base of A frag rows
  const int brow = ((wc << 6) + (l & 15)) << 6;   // byte base of B frag rows

#pragma unroll 1
  for (int p = 0; p < 16; ++p) {      // 16 phases of K=32 (Dm = 512)
    if (p < 15) { WAIT_BARRIER(4); }  // phase p's 4 loads done; p+1's in flight
    else        { WAIT_BARRIER(0); }
    __builtin_amdgcn_sched_barrier(0);
    if (p < 14) {
      const int slot = (p + 2) & 3;
      STAGE1(slot, p + 2);
    }
    const char* Ab = (const char*)As[p & 3];
    const char* Bb = (const char*)Bs[p & 3];
    short8 af[4], bfr[4];
#pragma unroll
    for (int mi = 0; mi < 4; ++mi)
      af[mi] = *(const short8*)(Ab + arow + (mi << 10) + kby);
#pragma unroll
    for (int ni = 0; ni < 4; ++ni)
      bfr[ni] = *(const short8*)(Bb + brow + (ni << 10) + kby);
    __builtin_amdgcn_s_setprio(1);
#pragma unroll
    for (int mi = 0; mi < 4; ++mi)
#pragma unroll
      for (int ni = 0; ni < 4; ++ni)
        acc[mi][ni] = mfma16(af[mi], bfr[ni], acc[mi][ni]);
    __builtin_amdgcn_s_setprio(0);
  }
#undef STAGE1

  const int row0 = tm + wr * 64 + ((l >> 4) << 2);
  const int col0 = tn + wc * 64 + ((l & 15) << 2);   // 4 contiguous output cols
  const size_t hb = (size_t)el * Fm;
  const float4 bv = *(const float4*)(bias + col0);

  // gelu(v)*wt with folded constants: g = v*rcp(1+exp2(v*(A + B*v^2)))
  const float Ac = -2.3022120f;    // -2*0.7978845608*log2(e)
  const float Bc = -0.10294341f;   // Ac*0.044715

#pragma unroll
  for (int mi = 0; mi < 4; ++mi) {
#pragma unroll
    for (int r = 0; r < 4; ++r) {
      const int rr = row0 + mi * 16 + r;
      const float wt = wts[(size_t)rr * 9 + eg];
      float g[4];
      const float bvv[4] = {bv.x, bv.y, bv.z, bv.w};
#pragma unroll
      for (int ni = 0; ni < 4; ++ni) {
        const float v = acc[mi][ni][r] + bvv[ni];
        const float t2 = v * fmaf(Bc, v * v, Ac);
        g[ni] = wt * v * fast_rcp(1.0f + fast_exp2(t2));
      }
      uint2 pk;
      asm("v_cvt_pk_bf16_f32 %0, %1, %2" : "=v"(pk.x) : "v"(g[0]), "v"(g[1]));
      asm("v_cvt_pk_bf16_f32 %0, %1, %2" : "=v"(pk.y) : "v"(g[2]), "v"(g[3]));
      *(uint2*)(Hs + (size_t)rr * ldH + hb + col0) = pk;   // 4 bf16, 8B coalesced
    }
  }
}

// ---------- GEMM2: out[m,d] (+)= Hs[m,0:Kt] @ W2Tg[d,0:Kt]^T  (+ gated bias on g0)
// 128(M) x 64(N) tile, BK=64, 4 waves (64x32/wave), register acc over concat-K.
// 3-stage LDS pipeline with counted vmcnt (T4): 12 loads in flight, fused
// wait+barrier (no vmcnt(0) drain mid-loop). Grid 512 = 2 blocks/CU.
// B-columns permuted (BPERM2) so each thread's 2 output cols are contiguous.

__global__ __launch_bounds__(256)
void gemm2_k(const unsigned short* __restrict__ A, int lda,
             const unsigned short* __restrict__ BT, int ldb,
             float* __restrict__ out,
             const float* __restrict__ wts,
             const float* __restrict__ b2, const float* __restrict__ bs2,
             int Kt, int g0) {
  __shared__ __attribute__((aligned(16))) unsigned short As[3][128 * 64];
  __shared__ __attribute__((aligned(16))) unsigned short Bs[3][64 * 64];

  const int tid = threadIdx.x, l = tid & 63, w = tid >> 6;
  const int wr = w >> 1, wc = w & 1;            // wave tile 64(M) x 32(N)
  const int wg = (blockIdx.x & 7) * 64 + (blockIdx.x >> 3);
  const int gm = wg >> 6;                       // m-group
  const int sub = wg & 63;                      // 8m x 8n, n fastest
  const int tn = (sub & 7) << 6;
  const int tm = ((gm << 3) + (sub >> 3)) << 7;

  f32x4 acc[4][2];
  const f32x4 zz = {0.f, 0.f, 0.f, 0.f};
#pragma unroll
  for (int mi = 0; mi < 4; ++mi)
#pragma unroll
    for (int ni = 0; ni < 2; ++ni) acc[mi][ni] = zz;

  const int srow = tid >> 3;                    // 0..31
  const int sc = ((tid & 7) ^ (srow & 7)) << 3;

  // 6 gload_lds per STAGE (4 A + 2 B)
#define STAGE2(buf, ks)                                                          \
  {                                                                              \
    _Pragma("unroll")                                                            \
    for (int i = 0; i < 4; ++i) {                                                \
      const int row = i * 32 + srow;                                             \
      gload_lds16(A + (size_t)(tm + row) * lda + (ks) + sc,                      \
                  (char*)As[buf] + i * 4096 + tid * 16);                         \
    }                                                                            \
    _Pragma("unroll")                                                            \
    for (int i = 0; i < 2; ++i) {                                                \
      const int row = i * 32 + srow;                                             \
      gload_lds16(BT + (size_t)(tn + BPERM2(row)) * ldb + (ks) + sc,             \
                  (char*)Bs[buf] + i * 4096 + tid * 16);                         \
    }                                                                            \
  }

  const int NT = Kt >> 6;
  STAGE2(0, 0);
  STAGE2(1, 64);

#pragma unroll 1
  for (int t = 0; t < NT; ++t) {
    const int cur = t % 3;
    // stage t complete; stage t+1's 6 loads may remain in flight
    if (t + 1 < NT) { WAIT_BARRIER(6); }
    else            { WAIT_BARRIER(0); }
    __builtin_amdgcn_sched_barrier(0);
    if (t + 2 < NT) {
      const int nb = (t + 2) % 3;
      STAGE2(nb, (t + 2) << 6);
    }
#pragma unroll
    for (int kk = 0; kk < 2; ++kk) {
      const int kbx = (kk * 64 + ((l >> 4) << 4)) ^ ((l & 7) << 4);
      short8 af[4], bfr[2];
#pragma unroll
      for (int mi = 0; mi < 4; ++mi)
        af[mi] = *(const short8*)((const char*)As[cur] + ((wr * 64 + mi * 16 + (l & 15)) << 7) + kbx);
#pragma unroll
      for (int ni = 0; ni < 2; ++ni)
        bfr[ni] = *(const short8*)((const char*)Bs[cur] + ((wc * 32 + ni * 16 + (l & 15)) << 7) + kbx);
#pragma unroll
      for (int mi = 0; mi < 4; ++mi)
#pragma unroll
        for (int ni = 0; ni < 2; ++ni)
          acc[mi][ni] = mfma16(af[mi], bfr[ni], acc[mi][ni]);
    }
  }
#undef STAGE2

  const int row0 = tm + wr * 64 + ((l >> 4) << 2);
  const int col0 = tn + wc * 32 + ((l & 15) << 1);   // 2 contiguous output cols

  if (g0) {
    float bcol[2][9];
#pragma unroll
    for (int ni = 0; ni < 2; ++ni) {
      const int c = col0 + ni;
#pragma unroll
      for (int e = 0; e < 8; ++e) bcol[ni][e] = b2[(e << 9) + c];
      bcol[ni][8] = bs2[c];
    }
#pragma unroll
    for (int mi = 0; mi < 4; ++mi)
#pragma unroll
      for (int r = 0; r < 4; ++r) {
        const int rr = row0 + mi * 16 + r;
        const float* wrow = wts + (size_t)rr * 9;
        float b0 = 0.f, b1v = 0.f;
#pragma unroll
        for (int e = 0; e < 9; ++e) { b0 += wrow[e] * bcol[0][e]; b1v += wrow[e] * bcol[1][e]; }
        float2 o;
        o.x = acc[mi][0][r] + b0;
        o.y = acc[mi][1][r] + b1v;
        *(float2*)(out + (size_t)rr * Dm + col0) = o;
      }
  } else {
#pragma unroll
    for (int mi = 0; mi < 4; ++mi)
#pragma unroll
      for (int r = 0; r < 4; ++r) {
        float* p = out + (size_t)(row0 + mi * 16 + r) * Dm + col0;
        float2 o = *(float2*)p;
        o.x += acc[mi][0][r];
        o.y += acc[mi][1][r];
        *(float2*)p = o;
      }
  }
}

// ---------- launch ----------

extern "C" void kernel_launch(void* const* d_in, const int* in_sizes, int n_in,
                              void* d_out, int out_size, void* d_ws, size_t ws_size,
                              hipStream_t stream) {
  const float* x   = (const float*)d_in[0];
  const float* gp  = (const float*)d_in[1];
  const float* sg  = (const float*)d_in[2];
  const float* W1  = (const float*)d_in[3];
  const float* b1  = (const float*)d_in[4];
  const float* W2  = (const float*)d_in[5];
  const float* b2  = (const float*)d_in[6];
  const float* Ws1 = (const float*)d_in[7];
  const float* bs1 = (const float*)d_in[8];
  const float* Ws2 = (const float*)d_in[9];
  const float* bs2 = (const float*)d_in[10];
  float* out = (float*)d_out;

  const size_t szXb  = (size_t)Mm * Dm * 2;        //  8,388,608
  const size_t szWts = (size_t)Mm * 9 * 4;         //    294,912
  const size_t szW1T = (size_t)9 * Fm * Dm * 2;    // 18,874,368
  const size_t szW2T = (size_t)9 * Fm * Dm * 2;    // 18,874,368
  const size_t base  = szXb + szWts + szW1T + szW2T;

  int G;
  if      (ws_size >= base + (size_t)Mm * 9 * Fm * 2) G = 9; // 348.4 MB
  else if (ws_size >= base + (size_t)Mm * 3 * Fm * 2) G = 3; // 147.1 MB
  else if (ws_size >= base + (size_t)Mm * 2 * Fm * 2) G = 2; // 113.5 MB
  else if (ws_size >= base + (size_t)Mm * 1 * Fm * 2) G = 1; //  80.0 MB
  else return;

  char* ws = (char*)d_ws;
  unsigned short* Xb  = (unsigned short*)(ws);
  float*          wts = (float*)(ws + szXb);
  unsigned short* W1T = (unsigned short*)(ws + szXb + szWts);
  unsigned short* W2T = (unsigned short*)(ws + szXb + szWts + szW1T);
  unsigned short* Hs  = (unsigned short*)(ws + base);
  const int ldH = G * Fm;

  cvtx_k<<<dim3((Mm * Dm) / 1024), dim3(256), 0, stream>>>(x, Xb, Mm * Dm);
  wts_k<<<dim3(Mm / 256), dim3(256), 0, stream>>>(gp, sg, wts);
  wt_k<<<dim3(2 * 9 * 1024), dim3(32, 8), 0, stream>>>(W1, Ws1, W2, Ws2, W1T, W2T);

  for (int gb = 0; gb < 9; gb += G) {
    const int Gg = (9 - gb < G) ? (9 - gb) : G;
    gemm1_k<<<dim3(Gg * 1024), dim3(256), 0, stream>>>(
        Xb, W1T, b1, bs1, wts, Hs, gb, Gg, ldH);
    gemm2_k<<<dim3(512), dim3(256), 0, stream>>>(
        Hs, ldH, W2T + (size_t)gb * Fm, KTOT, out, wts, b2, bs2, Gg * Fm, gb == 0 ? 1 : 0);
  }
}